// Round 3
// baseline (685.313 us; speedup 1.0000x reference)
//
#include <hip/hip_runtime.h>
#include <stdint.h>

// Problem constants
#define BATCH 4
#define NSEQ  2048
#define CDIM  1152
#define HB    16
#define DHD   72
#define D3    3456
#define NT    8192    // BATCH*NSEQ

typedef __attribute__((ext_vector_type(8))) short short8;       // 8 bf16 (4 VGPRs)
typedef __attribute__((ext_vector_type(8))) unsigned short u16x8;
typedef __attribute__((ext_vector_type(4))) float f32x4;

__device__ __forceinline__ float bf2f(unsigned short u) {
  return __uint_as_float(((unsigned)u) << 16);
}
__device__ __forceinline__ unsigned short f2bf(float f) {
  unsigned u = __float_as_uint(f);
  u += 0x7FFF + ((u >> 16) & 1);   // RNE
  return (unsigned short)(u >> 16);
}

// load 8 contiguous elements as bf16x8 (converting if fp32 source)
__device__ __forceinline__ short8 load8(const unsigned short* p) {
  return *(const short8*)p;
}
__device__ __forceinline__ short8 load8(const float* p) {
  f32x4 a = *(const f32x4*)p;
  f32x4 b = *(const f32x4*)(p + 4);
  short8 r;
#pragma unroll
  for (int i = 0; i < 4; i++) r[i] = (short)f2bf(a[i]);
#pragma unroll
  for (int i = 0; i < 4; i++) r[4 + i] = (short)f2bf(b[i]);
  return r;
}

// ---------------------------------------------------------------------------
// GEMM-BT: C[M,Dn] = A[M,K] * Bt[Dn,K]^T (+bias), fp32/bf16 in, fp32 acc.
// BM=BN=128, BK=32, 256 threads = 4 waves (2x2 of 64x64), 16x16x32 MFMA.
// SCATTER=1: epilogue scatters bf16 into qkv layout [s][b][h][n][72]
// (s=col/1152, h=(col%1152)/72, dh=col%72; b=row/2048, n=row%2048).
// SCATTER=0: plain fp32 output + fp32 bias.
// ---------------------------------------------------------------------------
template <typename TA, typename TB, int SCATTER>
__global__ __launch_bounds__(256) void gemm_bt(
    const TA* __restrict__ A, const TB* __restrict__ Bt,
    const float* __restrict__ bias, void* __restrict__ Cout,
    int M, int Dn, int K) {
  __shared__ __attribute__((aligned(16))) unsigned short sA[128 * 32];
  __shared__ __attribute__((aligned(16))) unsigned short sB[128 * 32];

  const int tid  = threadIdx.x;
  const int lane = tid & 63;
  const int w    = tid >> 6;
  const int wm   = w >> 1, wn = w & 1;
  const int quad = lane >> 4, l16 = lane & 15;
  const int m0 = blockIdx.y * 128, n0 = blockIdx.x * 128;

  const f32x4 zero = {0.f, 0.f, 0.f, 0.f};
  f32x4 acc[4][4];
#pragma unroll
  for (int i = 0; i < 4; i++)
#pragma unroll
    for (int j = 0; j < 4; j++) acc[i][j] = zero;

  for (int kt = 0; kt < K; kt += 32) {
    // stage 128x32 tiles as bf16 (512 8-elem chunks each, 2 per thread)
#pragma unroll
    for (int i = 0; i < 2; i++) {
      int c   = tid + 256 * i;
      int row = c >> 2;
      int col = (c & 3) << 3;
      short8 va = load8(A + (size_t)(m0 + row) * K + kt + col);
      *(short8*)(sA + row * 32 + col) = va;
      short8 vb = load8(Bt + (size_t)(n0 + row) * K + kt + col);
      *(short8*)(sB + row * 32 + col) = vb;
    }
    __syncthreads();

    short8 a[4], b[4];
#pragma unroll
    for (int i = 0; i < 4; i++)
      a[i] = *(const short8*)(sA + (wm * 64 + i * 16 + l16) * 32 + quad * 8);
#pragma unroll
    for (int j = 0; j < 4; j++)
      b[j] = *(const short8*)(sB + (wn * 64 + j * 16 + l16) * 32 + quad * 8);

#pragma unroll
    for (int i = 0; i < 4; i++)
#pragma unroll
      for (int j = 0; j < 4; j++)
        acc[i][j] = __builtin_amdgcn_mfma_f32_16x16x32_bf16(a[i], b[j], acc[i][j], 0, 0, 0);
    __syncthreads();
  }

  // epilogue: D row = quad*4+r, col = lane&15
#pragma unroll
  for (int i = 0; i < 4; i++) {
    int row = m0 + wm * 64 + i * 16 + quad * 4;
#pragma unroll
    for (int j = 0; j < 4; j++) {
      int col = n0 + wn * 64 + j * 16 + l16;
      if (SCATTER) {
        int s  = col / CDIM;
        int rm = col - s * CDIM;
        int h  = rm / DHD;
        int dh = rm - h * DHD;
        int b_ = row >> 11;           // rows of 4 never straddle the 2048 bdry
        int n  = row & 2047;
        unsigned short* Cb = (unsigned short*)Cout;
#pragma unroll
        for (int r = 0; r < 4; r++)
          Cb[(((size_t)(s * BATCH + b_) * HB + h) * NSEQ + (n + r)) * DHD + dh] =
              f2bf(acc[i][j][r]);
      } else {
        float bb = bias ? bias[col] : 0.f;
        float* Cf = (float*)Cout;
#pragma unroll
        for (int r = 0; r < 4; r++)
          Cf[(size_t)(row + r) * Dn + col] = acc[i][j][r] + bb;
      }
    }
  }
}

// ---------------------------------------------------------------------------
// RoPE (halves convention) + RMSNorm on q,k IN-PLACE on qkvb[s][b][h][n][72].
// One block per (b,n). V (s=2) untouched.
// ---------------------------------------------------------------------------
__global__ __launch_bounds__(256) void rope_rms(
    unsigned short* __restrict__ qkvb,
    const float* __restrict__ qw, const float* __restrict__ kw) {
  const int blk = blockIdx.x;
  const int b = blk >> 11;
  const int n = blk & 2047;
  const int tid = threadIdx.x;

  __shared__ float sv[CDIM];
  __shared__ float srsq[HB];

  const float nf = (float)n;
  const float l2t_over_half = 13.287712379549449f / 36.0f;  // log2(10000)/36

  for (int sel = 0; sel < 2; sel++) {
    const float* wnorm = sel ? kw : qw;

    for (int e = tid; e < CDIM; e += 256) {
      int h  = e / DHD;
      int dh = e - h * DHD;
      int i  = (dh < 36) ? dh : dh - 36;
      size_t ah = (((size_t)(sel * BATCH + b) * HB + h) * NSEQ + n) * DHD;
      float x1 = bf2f(qkvb[ah + i]);
      float x2 = bf2f(qkvb[ah + i + 36]);
      float inv_freq = exp2f(-l2t_over_half * (float)i);
      float ang = nf * inv_freq;
      float cs = cosf(ang), sn = sinf(ang);
      sv[e] = (dh < 36) ? (x1 * cs - x2 * sn) : (x2 * cs + x1 * sn);
    }
    __syncthreads();
    if (tid < HB) {
      float s = 0.f;
      for (int d = 0; d < DHD; d++) { float v = sv[tid * DHD + d]; s += v * v; }
      srsq[tid] = rsqrtf(s * (1.0f / 72.0f) + 1e-6f);
    }
    __syncthreads();
    for (int e = tid; e < CDIM; e += 256) {
      int h  = e / DHD;
      int dh = e - h * DHD;
      size_t ah = (((size_t)(sel * BATCH + b) * HB + h) * NSEQ + n) * DHD;
      qkvb[ah + dh] = f2bf(sv[e] * srsq[h] * wnorm[dh]);
    }
    __syncthreads();
  }
}

// ---------------------------------------------------------------------------
// Flash attention: block = (64 q-rows, head, batch), 4 waves x 16 q-rows.
// KV tiles of 64, head dim 72 (MFMA K padded to 96 with zeroed LDS cols).
// Online softmax per q-row; P round-trips LDS (C/D layout -> A-operand).
// ---------------------------------------------------------------------------
#define SKP 104   // sK row stride (96+8)
#define SVW 72    // sVt/sP row stride (64+8)
__global__ __launch_bounds__(256) void flash_attn(
    const unsigned short* __restrict__ qkvb, unsigned short* __restrict__ AO) {
  __shared__ __attribute__((aligned(16))) unsigned short sK[64 * SKP];
  __shared__ __attribute__((aligned(16))) unsigned short sVt[80 * SVW];
  __shared__ __attribute__((aligned(16))) unsigned short sP[64 * SVW];

  const int tid  = threadIdx.x;
  const int w    = tid >> 6;
  const int lane = tid & 63;
  const int quad = lane >> 4, l16 = lane & 15;
  const int q0 = blockIdx.x * 64;
  const int h = blockIdx.y, b = blockIdx.z;

  const unsigned short* Qb = qkvb + ((size_t)(0 * BATCH + b) * HB + h) * NSEQ * DHD;
  const unsigned short* Kb = qkvb + ((size_t)(1 * BATCH + b) * HB + h) * NSEQ * DHD;
  const unsigned short* Vb = qkvb + ((size_t)(2 * BATCH + b) * HB + h) * NSEQ * DHD;

  const u16x8 z8 = {0, 0, 0, 0, 0, 0, 0, 0};
  const short8 zs = {0, 0, 0, 0, 0, 0, 0, 0};

  // pre-zero sK cols 72..95 (persist: staging only writes cols 0..71)
  if (tid < 192) {
    int row = tid / 3, ch = tid % 3;
    *(u16x8*)(sK + row * SKP + DHD + ch * 8) = z8;
  }
  // pre-zero sVt rows 72..79 (only cols 0..63 are ever read)
  if (tid < 72) {
    int row = 72 + tid / 9, ch = tid % 9;
    *(u16x8*)(sVt + row * SVW + ch * 8) = z8;
  }

  // Q fragments (A-operand): rows q0+w*16+l16, k = kb*32+quad*8+j (k>=72 -> 0)
  short8 aq[3];
  {
    const unsigned short* qrow = Qb + (size_t)(q0 + w * 16 + l16) * DHD;
    aq[0] = *(const short8*)(qrow + 0 * 32 + quad * 8);
    aq[1] = *(const short8*)(qrow + 1 * 32 + quad * 8);
    aq[2] = (quad == 0) ? *(const short8*)(qrow + 64) : zs;
  }

  const f32x4 zero = {0.f, 0.f, 0.f, 0.f};
  float m_i[4], l_i[4];
  f32x4 o[5];
#pragma unroll
  for (int r = 0; r < 4; r++) { m_i[r] = -1e30f; l_i[r] = 0.f; }
#pragma unroll
  for (int nb = 0; nb < 5; nb++) o[nb] = zero;

  const float scale = 0.11785113019775793f;  // 72^-0.5

  for (int kv0 = 0; kv0 < NSEQ; kv0 += 64) {
    __syncthreads();
    // stage K tile [64][72] (9 8-elem chunks per row)
    for (int c = tid; c < 576; c += 256) {
      int kv = c / 9;
      int d0 = (c - kv * 9) * 8;
      u16x8 kvv = *(const u16x8*)(Kb + (size_t)(kv0 + kv) * DHD + d0);
      *(u16x8*)(sK + kv * SKP + d0) = kvv;
    }
    // stage V transposed [dh][kv]
    for (int c = tid; c < 576; c += 256) {
      int kv = c & 63;
      int d0 = (c >> 6) * 8;
      u16x8 vv = *(const u16x8*)(Vb + (size_t)(kv0 + kv) * DHD + d0);
#pragma unroll
      for (int j = 0; j < 8; j++) sVt[(d0 + j) * SVW + kv] = vv[j];
    }
    __syncthreads();

    // S = Q K^T (scaled)
    f32x4 st[4];
#pragma unroll
    for (int nk = 0; nk < 4; nk++) {
      f32x4 s = zero;
#pragma unroll
      for (int kb = 0; kb < 3; kb++) {
        short8 kf = *(const short8*)(sK + (nk * 16 + l16) * SKP + kb * 32 + quad * 8);
        s = __builtin_amdgcn_mfma_f32_16x16x32_bf16(aq[kb], kf, s, 0, 0, 0);
      }
#pragma unroll
      for (int r = 0; r < 4; r++) s[r] *= scale;
      st[nk] = s;
    }

    // online softmax: row = quad*4+r; 64 cols spread: lane holds col nk*16+l16
    float mnew[4], alpha[4], rsum[4];
#pragma unroll
    for (int r = 0; r < 4; r++) {
      float mx = fmaxf(fmaxf(st[0][r], st[1][r]), fmaxf(st[2][r], st[3][r]));
#pragma unroll
      for (int d = 1; d < 16; d <<= 1) mx = fmaxf(mx, __shfl_xor(mx, d, 64));
      mnew[r] = fmaxf(m_i[r], mx);
      alpha[r] = expf(m_i[r] - mnew[r]);
      rsum[r] = 0.f;
    }
#pragma unroll
    for (int nk = 0; nk < 4; nk++)
#pragma unroll
      for (int r = 0; r < 4; r++) {
        float p = expf(st[nk][r] - mnew[r]);
        st[nk][r] = p;
        rsum[r] += p;
      }
#pragma unroll
    for (int r = 0; r < 4; r++) {
      float s = rsum[r];
#pragma unroll
      for (int d = 1; d < 16; d <<= 1) s += __shfl_xor(s, d, 64);
      l_i[r] = l_i[r] * alpha[r] + s;
      m_i[r] = mnew[r];
    }

    // P (bf16) -> per-wave LDS region, C/D layout -> [row][col]
#pragma unroll
    for (int nk = 0; nk < 4; nk++)
#pragma unroll
      for (int r = 0; r < 4; r++)
        sP[(w * 16 + quad * 4 + r) * SVW + nk * 16 + l16] = f2bf(st[nk][r]);

    // rescale O
#pragma unroll
    for (int nb = 0; nb < 5; nb++)
#pragma unroll
      for (int r = 0; r < 4; r++) o[nb][r] *= alpha[r];

    // O += P V  (contraction over kv=64: 2 chunks of 32)
#pragma unroll
    for (int kb = 0; kb < 2; kb++) {
      short8 pf = *(const short8*)(sP + (w * 16 + l16) * SVW + kb * 32 + quad * 8);
#pragma unroll
      for (int nb = 0; nb < 5; nb++) {
        short8 vf = *(const short8*)(sVt + (nb * 16 + l16) * SVW + kb * 32 + quad * 8);
        o[nb] = __builtin_amdgcn_mfma_f32_16x16x32_bf16(pf, vf, o[nb], 0, 0, 0);
      }
    }
  }

  // epilogue: normalize and write AO[b, n, h*72+dh] (bf16)
  float inv[4];
#pragma unroll
  for (int r = 0; r < 4; r++) inv[r] = 1.0f / l_i[r];
  const int qrow = q0 + w * 16 + quad * 4;
#pragma unroll
  for (int nb = 0; nb < 5; nb++) {
    int dh = nb * 16 + l16;
    if (dh < DHD) {
#pragma unroll
      for (int r = 0; r < 4; r++)
        AO[((size_t)b * NSEQ + qrow + r) * CDIM + h * DHD + dh] = f2bf(o[nb][r] * inv[r]);
    }
  }
}

// ---------------------------------------------------------------------------
extern "C" void kernel_launch(void* const* d_in, const int* in_sizes, int n_in,
                              void* d_out, int out_size, void* d_ws, size_t ws_size,
                              hipStream_t stream) {
  const float* x      = (const float*)d_in[0];
  const float* w_qkv  = (const float*)d_in[1];
  const float* w_proj = (const float*)d_in[2];
  const float* b_proj = (const float*)d_in[3];
  const float* qnw    = (const float*)d_in[4];
  const float* knw    = (const float*)d_in[5];
  float* out = (float*)d_out;

  char* ws = (char*)d_ws;
  const size_t QKV_BYTES = (size_t)3 * BATCH * HB * NSEQ * DHD * 2;  // 56,623,104
  unsigned short* qkvb = (unsigned short*)(ws);
  unsigned short* AO   = (unsigned short*)(ws + QKV_BYTES);          // +18,874,368

  gemm_bt<float, float, 1><<<dim3(D3 / 128, NT / 128), 256, 0, stream>>>(
      x, w_qkv, nullptr, qkvb, NT, D3, CDIM);
  rope_rms<<<dim3(NT), 256, 0, stream>>>(qkvb, qnw, knw);
  flash_attn<<<dim3(NSEQ / 64, HB, BATCH), 256, 0, stream>>>(qkvb, AO);
  gemm_bt<unsigned short, float, 0><<<dim3(CDIM / 128, NT / 128), 256, 0, stream>>>(
      AO, w_proj, b_proj, out, NT, CDIM, CDIM);
}

// Round 4
// 535.431 us; speedup vs baseline: 1.2799x; 1.2799x over previous
//
#include <hip/hip_runtime.h>
#include <stdint.h>

// Problem constants
#define BATCH 4
#define NSEQ  2048
#define CDIM  1152
#define HB    16
#define DHD   72
#define D3    3456
#define NT    8192    // BATCH*NSEQ

typedef __attribute__((ext_vector_type(8))) short short8;       // 8 bf16 (4 VGPRs)
typedef __attribute__((ext_vector_type(8))) unsigned short u16x8;
typedef __attribute__((ext_vector_type(4))) float f32x4;

__device__ __forceinline__ float bf2f(unsigned short u) {
  return __uint_as_float(((unsigned)u) << 16);
}
__device__ __forceinline__ unsigned short f2bf(float f) {
  unsigned u = __float_as_uint(f);
  u += 0x7FFF + ((u >> 16) & 1);   // RNE
  return (unsigned short)(u >> 16);
}

// load 8 contiguous elements as bf16x8 (converting if fp32 source)
__device__ __forceinline__ short8 load8(const unsigned short* p) {
  return *(const short8*)p;
}
__device__ __forceinline__ short8 load8(const float* p) {
  f32x4 a = *(const f32x4*)p;
  f32x4 b = *(const f32x4*)(p + 4);
  short8 r;
#pragma unroll
  for (int i = 0; i < 4; i++) r[i] = (short)f2bf(a[i]);
#pragma unroll
  for (int i = 0; i < 4; i++) r[4 + i] = (short)f2bf(b[i]);
  return r;
}

// ---------------------------------------------------------------------------
// GEMM-BT: C[M,Dn] = A[M,K] * Bt[Dn,K]^T (+bias), fp32/bf16 in, fp32 acc.
// BM=BN=128, BK=32, 256 threads = 4 waves (2x2 of 64x64), 16x16x32 MFMA.
// SCATTER=1: epilogue scatters bf16: Q,K into qkvb[s][b][h][n][72],
// V TRANSPOSED into Vt[b][h][dh][n]. SCATTER=0: plain fp32 + fp32 bias.
// ---------------------------------------------------------------------------
template <typename TA, typename TB, int SCATTER>
__global__ __launch_bounds__(256) void gemm_bt(
    const TA* __restrict__ A, const TB* __restrict__ Bt,
    const float* __restrict__ bias, void* __restrict__ Cout,
    unsigned short* __restrict__ Vt, int M, int Dn, int K) {
  __shared__ __attribute__((aligned(16))) unsigned short sA[128 * 32];
  __shared__ __attribute__((aligned(16))) unsigned short sB[128 * 32];

  const int tid  = threadIdx.x;
  const int lane = tid & 63;
  const int w    = tid >> 6;
  const int wm   = w >> 1, wn = w & 1;
  const int quad = lane >> 4, l16 = lane & 15;
  const int m0 = blockIdx.y * 128, n0 = blockIdx.x * 128;

  const f32x4 zero = {0.f, 0.f, 0.f, 0.f};
  f32x4 acc[4][4];
#pragma unroll
  for (int i = 0; i < 4; i++)
#pragma unroll
    for (int j = 0; j < 4; j++) acc[i][j] = zero;

  for (int kt = 0; kt < K; kt += 32) {
#pragma unroll
    for (int i = 0; i < 2; i++) {
      int c   = tid + 256 * i;
      int row = c >> 2;
      int col = (c & 3) << 3;
      short8 va = load8(A + (size_t)(m0 + row) * K + kt + col);
      *(short8*)(sA + row * 32 + col) = va;
      short8 vb = load8(Bt + (size_t)(n0 + row) * K + kt + col);
      *(short8*)(sB + row * 32 + col) = vb;
    }
    __syncthreads();

    short8 a[4], b[4];
#pragma unroll
    for (int i = 0; i < 4; i++)
      a[i] = *(const short8*)(sA + (wm * 64 + i * 16 + l16) * 32 + quad * 8);
#pragma unroll
    for (int j = 0; j < 4; j++)
      b[j] = *(const short8*)(sB + (wn * 64 + j * 16 + l16) * 32 + quad * 8);

#pragma unroll
    for (int i = 0; i < 4; i++)
#pragma unroll
      for (int j = 0; j < 4; j++)
        acc[i][j] = __builtin_amdgcn_mfma_f32_16x16x32_bf16(a[i], b[j], acc[i][j], 0, 0, 0);
    __syncthreads();
  }

  // epilogue: D row = quad*4+r, col = lane&15
#pragma unroll
  for (int i = 0; i < 4; i++) {
    int row = m0 + wm * 64 + i * 16 + quad * 4;
#pragma unroll
    for (int j = 0; j < 4; j++) {
      int col = n0 + wn * 64 + j * 16 + l16;
      if (SCATTER) {
        int s  = col / CDIM;
        int rm = col - s * CDIM;
        int h  = rm / DHD;
        int dh = rm - h * DHD;
        int b_ = row >> 11;           // rows of 4 never straddle the 2048 bdry
        int n  = row & 2047;
        if (s == 2) {
#pragma unroll
          for (int r = 0; r < 4; r++)
            Vt[((size_t)(b_ * HB + h) * DHD + dh) * NSEQ + n + r] = f2bf(acc[i][j][r]);
        } else {
          unsigned short* Cb = (unsigned short*)Cout;
#pragma unroll
          for (int r = 0; r < 4; r++)
            Cb[(((size_t)(s * BATCH + b_) * HB + h) * NSEQ + (n + r)) * DHD + dh] =
                f2bf(acc[i][j][r]);
        }
      } else {
        float bb = bias ? bias[col] : 0.f;
        float* Cf = (float*)Cout;
#pragma unroll
        for (int r = 0; r < 4; r++)
          Cf[(size_t)(row + r) * Dn + col] = acc[i][j][r] + bb;
      }
    }
  }
}

// ---------------------------------------------------------------------------
// RoPE (halves convention) + RMSNorm on q,k IN-PLACE on qkvb[s][b][h][n][72].
// One block per (b,n).
// ---------------------------------------------------------------------------
__global__ __launch_bounds__(256) void rope_rms(
    unsigned short* __restrict__ qkvb,
    const float* __restrict__ qw, const float* __restrict__ kw) {
  const int blk = blockIdx.x;
  const int b = blk >> 11;
  const int n = blk & 2047;
  const int tid = threadIdx.x;

  __shared__ float sv[CDIM];
  __shared__ float srsq[HB];

  const float nf = (float)n;
  const float l2t_over_half = 13.287712379549449f / 36.0f;  // log2(10000)/36

  for (int sel = 0; sel < 2; sel++) {
    const float* wnorm = sel ? kw : qw;

    for (int e = tid; e < CDIM; e += 256) {
      int h  = e / DHD;
      int dh = e - h * DHD;
      int i  = (dh < 36) ? dh : dh - 36;
      size_t ah = (((size_t)(sel * BATCH + b) * HB + h) * NSEQ + n) * DHD;
      float x1 = bf2f(qkvb[ah + i]);
      float x2 = bf2f(qkvb[ah + i + 36]);
      float inv_freq = exp2f(-l2t_over_half * (float)i);
      float ang = nf * inv_freq;
      float sn, cs;
      __sincosf(ang, &sn, &cs);
      sv[e] = (dh < 36) ? (x1 * cs - x2 * sn) : (x2 * cs + x1 * sn);
    }
    __syncthreads();
    if (tid < HB) {
      float s = 0.f;
      for (int d = 0; d < DHD; d++) { float v = sv[tid * DHD + d]; s += v * v; }
      srsq[tid] = rsqrtf(s * (1.0f / 72.0f) + 1e-6f);
    }
    __syncthreads();
    for (int e = tid; e < CDIM; e += 256) {
      int h  = e / DHD;
      int dh = e - h * DHD;
      size_t ah = (((size_t)(sel * BATCH + b) * HB + h) * NSEQ + n) * DHD;
      qkvb[ah + dh] = f2bf(sv[e] * srsq[h] * wnorm[dh]);
    }
    __syncthreads();
  }
}

// ---------------------------------------------------------------------------
// Flash attention, no-max softmax (|S*scale| <= sqrt(72) by Cauchy-Schwarz
// since q,k are RMS-normed -> exp2 never overflows). Block = 128 q-rows x
// head x batch; 4 waves x (2 tiles of 16 q). KV tiles of 64. Row-sum l via
// ones-row 72 of V (MFMA computes it). P round-trips LDS per wave.
// ---------------------------------------------------------------------------
#define SKP 104   // sK row stride
#define SVW 72    // sVt/sP row stride (64 data + 8 pad)
__global__ __launch_bounds__(256) void flash_attn(
    const unsigned short* __restrict__ qkvb, const unsigned short* __restrict__ Vt,
    unsigned short* __restrict__ AO) {
  __shared__ __attribute__((aligned(16))) unsigned short sK[64 * SKP];   // 13312 B
  __shared__ __attribute__((aligned(16))) unsigned short sVt[80 * SVW];  // 11520 B
  __shared__ __attribute__((aligned(16))) unsigned short sP[64 * SVW];   //  9216 B

  const int tid  = threadIdx.x;
  const int w    = tid >> 6;
  const int lane = tid & 63;
  const int quad = lane >> 4, l16 = lane & 15;
  const int q0 = blockIdx.x * 128;
  const int h = blockIdx.y, b = blockIdx.z;

  const unsigned short* Qb = qkvb + ((size_t)(0 * BATCH + b) * HB + h) * NSEQ * DHD;
  const unsigned short* Kb = qkvb + ((size_t)(1 * BATCH + b) * HB + h) * NSEQ * DHD;
  const unsigned short* Vb = Vt + (size_t)(b * HB + h) * DHD * NSEQ;

  const u16x8 z8 = {0, 0, 0, 0, 0, 0, 0, 0};
  const short8 zs = {0, 0, 0, 0, 0, 0, 0, 0};

  // one-time LDS inits (ordered before any read by the staging barrier)
  if (tid < 192) {  // sK cols 72..95 = 0 (staging only writes cols 0..71)
    int row = tid / 3, ch = tid % 3;
    *(u16x8*)(sK + row * SKP + DHD + ch * 8) = z8;
  }
  if (tid < 64) sVt[72 * SVW + tid] = 0x3F80;  // ones row -> l via MFMA
  else if (tid < 120) {                        // rows 73..79 = 0
    int idx = tid - 64;
    *(u16x8*)(sVt + (73 + idx / 8) * SVW + (idx % 8) * 8) = z8;
  }

  // Q fragments: 2 q-tiles per wave, rows q0 + w*32 + qt*16 + l16
  short8 aq[2][3];
#pragma unroll
  for (int qt = 0; qt < 2; qt++) {
    const unsigned short* qrow = Qb + (size_t)(q0 + w * 32 + qt * 16 + l16) * DHD;
    aq[qt][0] = *(const short8*)(qrow + quad * 8);
    aq[qt][1] = *(const short8*)(qrow + 32 + quad * 8);
    aq[qt][2] = (quad == 0) ? *(const short8*)(qrow + 64) : zs;
  }

  const f32x4 zero = {0.f, 0.f, 0.f, 0.f};
  f32x4 o[2][5];
#pragma unroll
  for (int qt = 0; qt < 2; qt++)
#pragma unroll
    for (int nb = 0; nb < 5; nb++) o[qt][nb] = zero;

  const float scale2 = 0.17002329230297715f;  // 72^-0.5 * log2(e)

  for (int kv0 = 0; kv0 < NSEQ; kv0 += 64) {
    __syncthreads();
    // stage K tile [64][72]
    for (int c = tid; c < 576; c += 256) {
      int kv = c / 9;
      int d0 = (c - kv * 9) * 8;
      u16x8 kvv = *(const u16x8*)(Kb + (size_t)(kv0 + kv) * DHD + d0);
      *(u16x8*)(sK + kv * SKP + d0) = kvv;
    }
    // stage V^T tile [72][64] (pre-transposed in global -> vector LDS stores)
    for (int c = tid; c < 576; c += 256) {
      int dh = c >> 3;
      int kv = (c & 7) * 8;
      u16x8 vv = *(const u16x8*)(Vb + (size_t)dh * NSEQ + kv0 + kv);
      *(u16x8*)(sVt + dh * SVW + kv) = vv;
    }
    __syncthreads();

#pragma unroll
    for (int qt = 0; qt < 2; qt++) {
      // S = Q K^T
      f32x4 st[4];
#pragma unroll
      for (int nk = 0; nk < 4; nk++) {
        f32x4 s = zero;
#pragma unroll
        for (int kb = 0; kb < 3; kb++) {
          short8 kf = *(const short8*)(sK + (nk * 16 + l16) * SKP + kb * 32 + quad * 8);
          s = __builtin_amdgcn_mfma_f32_16x16x32_bf16(aq[qt][kb], kf, s, 0, 0, 0);
        }
        st[nk] = s;
      }
      // P = exp2(S * scale2), bf16, into per-wave LDS (C/D -> A layout)
#pragma unroll
      for (int nk = 0; nk < 4; nk++)
#pragma unroll
        for (int r = 0; r < 4; r++)
          sP[(w * 16 + quad * 4 + r) * SVW + nk * 16 + l16] =
              f2bf(exp2f(st[nk][r] * scale2));
      // O += P V
#pragma unroll
      for (int kb = 0; kb < 2; kb++) {
        short8 pf = *(const short8*)(sP + (w * 16 + l16) * SVW + kb * 32 + quad * 8);
#pragma unroll
        for (int nb = 0; nb < 5; nb++) {
          short8 vf = *(const short8*)(sVt + (nb * 16 + l16) * SVW + kb * 32 + quad * 8);
          o[qt][nb] = __builtin_amdgcn_mfma_f32_16x16x32_bf16(pf, vf, o[qt][nb], 0, 0, 0);
        }
      }
    }
  }

  // epilogue: l sits at dh=72 (nb=4, l16=8); broadcast within quad, normalize
#pragma unroll
  for (int qt = 0; qt < 2; qt++) {
    float inv[4];
#pragma unroll
    for (int r = 0; r < 4; r++)
      inv[r] = 1.0f / __shfl(o[qt][4][r], (quad << 4) + 8, 64);
    const int qrow = q0 + w * 32 + qt * 16 + quad * 4;
#pragma unroll
    for (int nb = 0; nb < 5; nb++) {
      int dh = nb * 16 + l16;
      if (dh < DHD) {
#pragma unroll
        for (int r = 0; r < 4; r++)
          AO[((size_t)b * NSEQ + qrow + r) * CDIM + h * DHD + dh] =
              f2bf(o[qt][nb][r] * inv[r]);
      }
    }
  }
}

// ---------------------------------------------------------------------------
extern "C" void kernel_launch(void* const* d_in, const int* in_sizes, int n_in,
                              void* d_out, int out_size, void* d_ws, size_t ws_size,
                              hipStream_t stream) {
  const float* x      = (const float*)d_in[0];
  const float* w_qkv  = (const float*)d_in[1];
  const float* w_proj = (const float*)d_in[2];
  const float* b_proj = (const float*)d_in[3];
  const float* qnw    = (const float*)d_in[4];
  const float* knw    = (const float*)d_in[5];
  float* out = (float*)d_out;

  char* ws = (char*)d_ws;
  const size_t HEAD_BYTES = (size_t)BATCH * HB * NSEQ * DHD * 2;  // 18,874,368
  unsigned short* qkvb = (unsigned short*)(ws);                   // Q,K: 2x
  unsigned short* Vt   = (unsigned short*)(ws + 2 * HEAD_BYTES);  // V^T
  unsigned short* AO   = (unsigned short*)(ws + 3 * HEAD_BYTES);  // attn out

  gemm_bt<float, float, 1><<<dim3(D3 / 128, NT / 128), 256, 0, stream>>>(
      x, w_qkv, nullptr, qkvb, Vt, NT, D3, CDIM);
  rope_rms<<<dim3(NT), 256, 0, stream>>>(qkvb, qnw, knw);
  flash_attn<<<dim3(NSEQ / 128, HB, BATCH), 256, 0, stream>>>(qkvb, Vt, AO);
  gemm_bt<unsigned short, float, 0><<<dim3(CDIM / 128, NT / 128), 256, 0, stream>>>(
      AO, w_proj, b_proj, out, nullptr, NT, CDIM, CDIM);
}

// Round 5
// 472.843 us; speedup vs baseline: 1.4493x; 1.1324x over previous
//
#include <hip/hip_runtime.h>
#include <stdint.h>

// Problem constants
#define BATCH 4
#define NSEQ  2048
#define CDIM  1152
#define HB    16
#define DHD   72
#define D3    3456
#define NT    8192    // BATCH*NSEQ

typedef __attribute__((ext_vector_type(8))) short short8;       // 8 bf16 (4 VGPRs)
typedef __attribute__((ext_vector_type(8))) unsigned short u16x8;
typedef __attribute__((ext_vector_type(4))) unsigned short u16x4;
typedef __attribute__((ext_vector_type(4))) float f32x4;

__device__ __forceinline__ float bf2f(unsigned short u) {
  return __uint_as_float(((unsigned)u) << 16);
}
__device__ __forceinline__ unsigned short f2bf(float f) {
  unsigned u = __float_as_uint(f);
  u += 0x7FFF + ((u >> 16) & 1);   // RNE
  return (unsigned short)(u >> 16);
}

// async 16B global->LDS copy: per-lane global addr, LDS dest = base + lane*16
__device__ __forceinline__ void gload_lds16(const unsigned short* g, unsigned short* l) {
  __builtin_amdgcn_global_load_lds(
      (const __attribute__((address_space(1))) void*)g,
      (__attribute__((address_space(3))) void*)l, 16, 0, 0);
}

// ---------------------------------------------------------------------------
// fp32 -> bf16 conversion prepass for x, w_qkv, w_proj (memory-bound).
// ---------------------------------------------------------------------------
#define XN    ((size_t)NT * CDIM)        // 9,437,184
#define WQN   ((size_t)D3 * CDIM)        // 3,981,312
#define WPN   ((size_t)CDIM * CDIM)      // 1,327,104
#define CVT_CHUNKS ((XN + WQN + WPN) / 4)  // 3,686,400 float4 chunks

__global__ __launch_bounds__(256) void cvt_bf16(
    const float* __restrict__ x, const float* __restrict__ wq,
    const float* __restrict__ wp, unsigned short* __restrict__ xb,
    unsigned short* __restrict__ wqb, unsigned short* __restrict__ wpb) {
  size_t c = (size_t)blockIdx.x * 256 + threadIdx.x;
  if (c >= CVT_CHUNKS) return;
  const float* src;
  unsigned short* dst;
  size_t e = c * 4;
  if (e < XN) { src = x + e; dst = xb + e; }
  else if (e < XN + WQN) { src = wq + (e - XN); dst = wqb + (e - XN); }
  else { src = wp + (e - XN - WQN); dst = wpb + (e - XN - WQN); }
  f32x4 v = *(const f32x4*)src;
  u16x4 r;
#pragma unroll
  for (int i = 0; i < 4; i++) r[i] = f2bf(v[i]);
  *(u16x4*)dst = r;
}

// ---------------------------------------------------------------------------
// GEMM-BT (bf16 in): C[M,Dn] = A[M,K]*Bt[Dn,K]^T (+bias), fp32 acc.
// BM=BN=128, BK=32, 256 thr = 4 waves (2x2 of 64x64), 16x16x32 MFMA,
// global_load_lds width-16 staging (m97 structure).
// SCATTER=1: bf16 scatter: Q,K -> qkvb[s][b][h][n][72], V -> Vt[b][h][dh][n].
// SCATTER=0: fp32 out + fp32 bias.
// ---------------------------------------------------------------------------
template <int SCATTER>
__global__ __launch_bounds__(256) void gemm_bt(
    const unsigned short* __restrict__ A, const unsigned short* __restrict__ Bt,
    const float* __restrict__ bias, void* __restrict__ Cout,
    unsigned short* __restrict__ Vt, int M, int Dn, int K) {
  __shared__ __attribute__((aligned(16))) unsigned short sA[128 * 32];
  __shared__ __attribute__((aligned(16))) unsigned short sB[128 * 32];

  const int tid  = threadIdx.x;
  const int lane = tid & 63;
  const int w    = tid >> 6;
  const int wm   = w >> 1, wn = w & 1;
  const int quad = lane >> 4, l16 = lane & 15;
  const int m0 = blockIdx.y * 128, n0 = blockIdx.x * 128;

  // staging addresses: wave w copies 16-row chunks {2w,2w+1} of A and B.
  // chunk ck: lane i -> row ck*16 + i/4, col (i%4)*8  (1024 B contiguous LDS)
  const int srow = (lane >> 2);
  const int scol = (lane & 3) << 3;

  const f32x4 zero = {0.f, 0.f, 0.f, 0.f};
  f32x4 acc[4][4];
#pragma unroll
  for (int i = 0; i < 4; i++)
#pragma unroll
    for (int j = 0; j < 4; j++) acc[i][j] = zero;

  for (int kt = 0; kt < K; kt += 32) {
#pragma unroll
    for (int i = 0; i < 2; i++) {
      int ck = w * 2 + i;
      gload_lds16(A + (size_t)(m0 + ck * 16 + srow) * K + kt + scol, sA + ck * 512);
      gload_lds16(Bt + (size_t)(n0 + ck * 16 + srow) * K + kt + scol, sB + ck * 512);
    }
    __syncthreads();

    short8 a[4], b[4];
#pragma unroll
    for (int i = 0; i < 4; i++)
      a[i] = *(const short8*)(sA + (wm * 64 + i * 16 + l16) * 32 + quad * 8);
#pragma unroll
    for (int j = 0; j < 4; j++)
      b[j] = *(const short8*)(sB + (wn * 64 + j * 16 + l16) * 32 + quad * 8);

#pragma unroll
    for (int i = 0; i < 4; i++)
#pragma unroll
      for (int j = 0; j < 4; j++)
        acc[i][j] = __builtin_amdgcn_mfma_f32_16x16x32_bf16(a[i], b[j], acc[i][j], 0, 0, 0);
    __syncthreads();
  }

  // epilogue: D row = quad*4+r, col = lane&15
#pragma unroll
  for (int i = 0; i < 4; i++) {
    int row = m0 + wm * 64 + i * 16 + quad * 4;
#pragma unroll
    for (int j = 0; j < 4; j++) {
      int col = n0 + wn * 64 + j * 16 + l16;
      if (SCATTER) {
        int s  = col / CDIM;
        int rm = col - s * CDIM;
        int h  = rm / DHD;
        int dh = rm - h * DHD;
        int b_ = row >> 11;           // rows of 4 never straddle the 2048 bdry
        int n  = row & 2047;
        if (s == 2) {
#pragma unroll
          for (int r = 0; r < 4; r++)
            Vt[((size_t)(b_ * HB + h) * DHD + dh) * NSEQ + n + r] = f2bf(acc[i][j][r]);
        } else {
          unsigned short* Cb = (unsigned short*)Cout;
#pragma unroll
          for (int r = 0; r < 4; r++)
            Cb[(((size_t)(s * BATCH + b_) * HB + h) * NSEQ + (n + r)) * DHD + dh] =
                f2bf(acc[i][j][r]);
        }
      } else {
        float bb = bias ? bias[col] : 0.f;
        float* Cf = (float*)Cout;
#pragma unroll
        for (int r = 0; r < 4; r++)
          Cf[(size_t)(row + r) * Dn + col] = acc[i][j][r] + bb;
      }
    }
  }
}

// ---------------------------------------------------------------------------
// RoPE (halves convention) + RMSNorm on q,k IN-PLACE on qkvb[s][b][h][n][72].
// One block per (b,n).
// ---------------------------------------------------------------------------
__global__ __launch_bounds__(256) void rope_rms(
    unsigned short* __restrict__ qkvb,
    const float* __restrict__ qw, const float* __restrict__ kw) {
  const int blk = blockIdx.x;
  const int b = blk >> 11;
  const int n = blk & 2047;
  const int tid = threadIdx.x;

  __shared__ float sv[CDIM];
  __shared__ float srsq[HB];

  const float nf = (float)n;
  const float l2t_over_half = 13.287712379549449f / 36.0f;  // log2(10000)/36

  for (int sel = 0; sel < 2; sel++) {
    const float* wnorm = sel ? kw : qw;

    for (int e = tid; e < CDIM; e += 256) {
      int h  = e / DHD;
      int dh = e - h * DHD;
      int i  = (dh < 36) ? dh : dh - 36;
      size_t ah = (((size_t)(sel * BATCH + b) * HB + h) * NSEQ + n) * DHD;
      float x1 = bf2f(qkvb[ah + i]);
      float x2 = bf2f(qkvb[ah + i + 36]);
      float inv_freq = exp2f(-l2t_over_half * (float)i);
      float ang = nf * inv_freq;
      float sn, cs;
      __sincosf(ang, &sn, &cs);
      sv[e] = (dh < 36) ? (x1 * cs - x2 * sn) : (x2 * cs + x1 * sn);
    }
    __syncthreads();
    if (tid < HB) {
      float s = 0.f;
      for (int d = 0; d < DHD; d++) { float v = sv[tid * DHD + d]; s += v * v; }
      srsq[tid] = rsqrtf(s * (1.0f / 72.0f) + 1e-6f);
    }
    __syncthreads();
    for (int e = tid; e < CDIM; e += 256) {
      int h  = e / DHD;
      int dh = e - h * DHD;
      size_t ah = (((size_t)(sel * BATCH + b) * HB + h) * NSEQ + n) * DHD;
      qkvb[ah + dh] = f2bf(sv[e] * srsq[h] * wnorm[dh]);
    }
    __syncthreads();
  }
}

// ---------------------------------------------------------------------------
// Flash attention, no-max softmax (|S*scale| <= sqrt(72) by Cauchy-Schwarz
// since q,k are RMS-normed -> exp2 never overflows). Block = 128 q-rows x
// head x batch; 4 waves x (2 tiles of 16 q). KV tiles of 64. Row-sum l via
// ones-row 72 of V (MFMA computes it). P round-trips LDS per wave.
// ---------------------------------------------------------------------------
#define SKP 104   // sK row stride
#define SVW 72    // sVt row stride (64 data + 8 pad)
#define SPW 68    // sP row stride: 136 B = 8-bank offset/row -> conflict-free writes
__global__ __launch_bounds__(256) void flash_attn(
    const unsigned short* __restrict__ qkvb, const unsigned short* __restrict__ Vt,
    unsigned short* __restrict__ AO) {
  __shared__ __attribute__((aligned(16))) unsigned short sK[64 * SKP];   // 13312 B
  __shared__ __attribute__((aligned(16))) unsigned short sVt[80 * SVW];  // 11520 B
  __shared__ __attribute__((aligned(16))) unsigned short sP[64 * SPW];   //  8704 B

  const int tid  = threadIdx.x;
  const int w    = tid >> 6;
  const int lane = tid & 63;
  const int quad = lane >> 4, l16 = lane & 15;
  const int q0 = blockIdx.x * 128;
  const int h = blockIdx.y, b = blockIdx.z;

  const unsigned short* Qb = qkvb + ((size_t)(0 * BATCH + b) * HB + h) * NSEQ * DHD;
  const unsigned short* Kb = qkvb + ((size_t)(1 * BATCH + b) * HB + h) * NSEQ * DHD;
  const unsigned short* Vb = Vt + (size_t)(b * HB + h) * DHD * NSEQ;

  const u16x8 z8 = {0, 0, 0, 0, 0, 0, 0, 0};
  const short8 zs = {0, 0, 0, 0, 0, 0, 0, 0};

  // one-time LDS inits (ordered before any read by the staging barrier)
  if (tid < 192) {  // sK cols 72..95 = 0 (staging only writes cols 0..71)
    int row = tid / 3, ch = tid % 3;
    *(u16x8*)(sK + row * SKP + DHD + ch * 8) = z8;
  }
  if (tid < 64) sVt[72 * SVW + tid] = 0x3F80;  // ones row -> l via MFMA
  else if (tid < 120) {                        // rows 73..79 = 0
    int idx = tid - 64;
    *(u16x8*)(sVt + (73 + idx / 8) * SVW + (idx % 8) * 8) = z8;
  }

  // Q fragments: 2 q-tiles per wave, rows q0 + w*32 + qt*16 + l16
  short8 aq[2][3];
#pragma unroll
  for (int qt = 0; qt < 2; qt++) {
    const unsigned short* qrow = Qb + (size_t)(q0 + w * 32 + qt * 16 + l16) * DHD;
    aq[qt][0] = *(const short8*)(qrow + quad * 8);
    aq[qt][1] = *(const short8*)(qrow + 32 + quad * 8);
    aq[qt][2] = (quad == 0) ? *(const short8*)(qrow + 64) : zs;
  }

  const f32x4 zero = {0.f, 0.f, 0.f, 0.f};
  f32x4 o[2][5];
#pragma unroll
  for (int qt = 0; qt < 2; qt++)
#pragma unroll
    for (int nb = 0; nb < 5; nb++) o[qt][nb] = zero;

  const float scale2 = 0.17002329230297715f;  // 72^-0.5 * log2(e)

  for (int kv0 = 0; kv0 < NSEQ; kv0 += 64) {
    __syncthreads();
    // stage K tile [64][72]
    for (int c = tid; c < 576; c += 256) {
      int kv = c / 9;
      int d0 = (c - kv * 9) * 8;
      u16x8 kvv = *(const u16x8*)(Kb + (size_t)(kv0 + kv) * DHD + d0);
      *(u16x8*)(sK + kv * SKP + d0) = kvv;
    }
    // stage V^T tile [72][64] (pre-transposed in global -> vector LDS stores)
    for (int c = tid; c < 576; c += 256) {
      int dh = c >> 3;
      int kv = (c & 7) * 8;
      u16x8 vv = *(const u16x8*)(Vb + (size_t)dh * NSEQ + kv0 + kv);
      *(u16x8*)(sVt + dh * SVW + kv) = vv;
    }
    __syncthreads();

#pragma unroll
    for (int qt = 0; qt < 2; qt++) {
      // S = Q K^T
      f32x4 st[4];
#pragma unroll
      for (int nk = 0; nk < 4; nk++) {
        f32x4 s = zero;
#pragma unroll
        for (int kb = 0; kb < 3; kb++) {
          short8 kf = *(const short8*)(sK + (nk * 16 + l16) * SKP + kb * 32 + quad * 8);
          s = __builtin_amdgcn_mfma_f32_16x16x32_bf16(aq[qt][kb], kf, s, 0, 0, 0);
        }
        st[nk] = s;
      }
      // P = exp2(S * scale2), bf16, into per-wave LDS (C/D -> A layout)
#pragma unroll
      for (int nk = 0; nk < 4; nk++)
#pragma unroll
        for (int r = 0; r < 4; r++)
          sP[(w * 16 + quad * 4 + r) * SPW + nk * 16 + l16] =
              f2bf(exp2f(st[nk][r] * scale2));
      // O += P V
#pragma unroll
      for (int kb = 0; kb < 2; kb++) {
        short8 pf = *(const short8*)(sP + (w * 16 + l16) * SPW + kb * 32 + quad * 8);
#pragma unroll
        for (int nb = 0; nb < 5; nb++) {
          short8 vf = *(const short8*)(sVt + (nb * 16 + l16) * SVW + kb * 32 + quad * 8);
          o[qt][nb] = __builtin_amdgcn_mfma_f32_16x16x32_bf16(pf, vf, o[qt][nb], 0, 0, 0);
        }
      }
    }
  }

  // epilogue: l sits at dh=72 (nb=4, l16=8); broadcast within quad, normalize
#pragma unroll
  for (int qt = 0; qt < 2; qt++) {
    float inv[4];
#pragma unroll
    for (int r = 0; r < 4; r++)
      inv[r] = 1.0f / __shfl(o[qt][4][r], (quad << 4) + 8, 64);
    const int qrow = q0 + w * 32 + qt * 16 + quad * 4;
#pragma unroll
    for (int nb = 0; nb < 5; nb++) {
      int dh = nb * 16 + l16;
      if (dh < DHD) {
#pragma unroll
        for (int r = 0; r < 4; r++)
          AO[((size_t)b * NSEQ + qrow + r) * CDIM + h * DHD + dh] =
              f2bf(o[qt][nb][r] * inv[r]);
      }
    }
  }
}

// ---------------------------------------------------------------------------
extern "C" void kernel_launch(void* const* d_in, const int* in_sizes, int n_in,
                              void* d_out, int out_size, void* d_ws, size_t ws_size,
                              hipStream_t stream) {
  const float* x      = (const float*)d_in[0];
  const float* w_qkv  = (const float*)d_in[1];
  const float* w_proj = (const float*)d_in[2];
  const float* b_proj = (const float*)d_in[3];
  const float* qnw    = (const float*)d_in[4];
  const float* knw    = (const float*)d_in[5];
  float* out = (float*)d_out;

  char* ws = (char*)d_ws;
  // layout (bytes): xb 18.9M | wqkvb 8.0M | wprojb 2.7M | qkvb 37.7M | Vt 18.9M
  // AO aliases xb (xb dead after gemm1). Total 86.1 MB.
  unsigned short* xb    = (unsigned short*)(ws);
  unsigned short* wqkvb = (unsigned short*)(ws + 18874368);
  unsigned short* wprojb= (unsigned short*)(ws + 26836992);
  unsigned short* qkvb  = (unsigned short*)(ws + 29491200);
  unsigned short* Vt    = (unsigned short*)(ws + 67239936);
  unsigned short* AO    = xb;

  cvt_bf16<<<dim3((CVT_CHUNKS + 255) / 256), 256, 0, stream>>>(
      x, w_qkv, w_proj, xb, wqkvb, wprojb);
  gemm_bt<1><<<dim3(D3 / 128, NT / 128), 256, 0, stream>>>(
      xb, wqkvb, nullptr, qkvb, Vt, NT, D3, CDIM);
  rope_rms<<<dim3(NT), 256, 0, stream>>>(qkvb, qnw, knw);
  flash_attn<<<dim3(NSEQ / 128, HB, BATCH), 256, 0, stream>>>(qkvb, Vt, AO);
  gemm_bt<0><<<dim3(CDIM / 128, NT / 128), 256, 0, stream>>>(
      AO, wprojb, b_proj, out, nullptr, NT, CDIM, CDIM);
}